// Round 4
// baseline (230.418 us; speedup 1.0000x reference)
//
#include <hip/hip_runtime.h>

typedef unsigned short u16;
typedef unsigned int u32;
typedef __attribute__((ext_vector_type(8))) short bfrag_t;   // 8 bf16 (4 VGPRs)
typedef __attribute__((ext_vector_type(4))) float accfrag_t; // 4 fp32
typedef __attribute__((ext_vector_type(4))) u32 u32x4;

// ---------- bf16 helpers ----------
__device__ __forceinline__ u16 f2b(float f) {
    u32 u = __float_as_uint(f);
    u32 r = (u + 0x7FFFu + ((u >> 16) & 1u)) >> 16;
    return (u16)r;
}
// pack 2 f32 -> 2 bf16 in one instruction (lo -> bits[15:0], hi -> bits[31:16])
__device__ __forceinline__ u32 pkbf16(float lo, float hi) {
    u32 r;
    asm("v_cvt_pk_bf16_f32 %0, %1, %2" : "=v"(r) : "v"(lo), "v"(hi));
    return r;
}
__device__ __forceinline__ float blo(u32 v) { return __uint_as_float(v << 16); }
__device__ __forceinline__ float bhi(u32 v) { return __uint_as_float(v & 0xffff0000u); }

// ---------- async global->LDS, 16B per lane ----------
__device__ __forceinline__ void load16(const u16* g, u16* l) {
    __builtin_amdgcn_global_load_lds(
        (__attribute__((address_space(1))) void*)(u16*)g,
        (__attribute__((address_space(3))) void*)l,
        16, 0, 0);
}

// ============================================================
// Merged prep: range dispatch, 1153 blocks. (identical to R2/R3 pass)
// ============================================================
__global__ __launch_bounds__(256) void k_prep(
    const float* __restrict__ x, const float* __restrict__ W1,
    const float* __restrict__ W2, const float* __restrict__ W3,
    const float* __restrict__ b2, u16* __restrict__ xtp,
    u16* __restrict__ W1f, u16* __restrict__ W2f,
    u16* __restrict__ W3f, float* __restrict__ b2p) {
    __shared__ __align__(16) char smem[29184];
    const int bid = blockIdx.x;
    const int tid = threadIdx.x;
    if (bid < 928) {             // ---- xtp ----
        const int b = bid / 116;
        const int r = bid - b * 116;
        const int hp = r >> 1;           // 0..57
        const int ch = r & 1;            // c-half: c0 = ch*128
        u16* rowbase = xtp + (size_t)(b * 58 + hp) * 58 * 256;
        if (hp == 0 || hp == 57) {       // zero border row (ch==0 does it all)
            if (ch == 0) {
                u32* p = (u32*)rowbase;
                for (int i = tid; i < 58 * 128; i += 256) p[i] = 0;
            }
            return;
        }
        float* lds = (float*)smem;       // [cl:128][w:57]  (odd stride: conflict-free)
        const int h = hp - 1;
        const int c0 = ch * 128;
        const float* xb = x + (size_t)(b * 256 + c0) * 3136 + h * 56;
#pragma unroll
        for (int it = 0; it < 7; ++it) {
            const int idx = it * 256 + tid;
            const int cl = idx / 14;
            const int f4 = idx - cl * 14;
            const float4 v = *(const float4*)(xb + (size_t)cl * 3136 + f4 * 4);
            float* d = lds + cl * 57 + f4 * 4;
            d[0] = v.x; d[1] = v.y; d[2] = v.z; d[3] = v.w;
        }
        __syncthreads();
        u32* orow = (u32*)rowbase;
        const int cp = tid & 63;
        const int wg = tid >> 6;
        const float* l0p = lds + (2 * cp) * 57;
        const float* l1p = lds + (2 * cp + 1) * 57;
#pragma unroll
        for (int it = 0; it < 15; ++it) {
            const int wp = it * 4 + wg;  // 0..59
            if (wp < 58) {
                u32 val = 0;
                if (wp >= 1 && wp <= 56) val = pkbf16(l0p[wp - 1], l1p[wp - 1]);
                orow[wp * 128 + ch * 64 + cp] = val;
            }
        }
    } else if (bid < 1072) {     // ---- W1 / W3 pack ----
        int b = bid - 928;
        const float* in = b < 72 ? W1 : W3;
        u16* out = b < 72 ? W1f : W3f;
        if (b >= 72) b -= 72;
        const int rrp = b >> 3;          // 0..8
        const int cg = b & 7;            // c-group of 32
        u16* lds1 = (u16*)smem;          // [q:32][n:256]
#pragma unroll
        for (int cc = 0; cc < 32; ++cc) {
            int d = (cg * 32 + cc) * 9 + rrp;
            lds1[cc * 256 + tid] = f2b(in[d * 256 + tid]);
        }
        __syncthreads();
        const int kc72 = rrp * 8 + cg;
#pragma unroll
        for (int s = 0; s < 32; ++s) {
            const int w = s >> 2;
            const int o = (s & 3) * 256 + tid;    // 0..1023 within [j][lane][e]
            const int e = o & 7;
            const int ln = (o >> 3) & 63;
            const int j = o >> 9;
            const int n = w * 32 + j * 16 + (ln & 15);
            const int q = (ln >> 4) * 8 + e;
            out[(w * 72 + kc72) * 1024 + o] = lds1[q * 256 + n];
        }
    } else if (bid < 1144) {     // ---- W2 pack ----
        const int b = bid - 1072;
        const int rr = b >> 3;
        const int w = b & 7;
        u16* lds2 = (u16*)smem;          // [k:256][dloc:32]
#pragma unroll
        for (int s = 0; s < 32; ++s) {
            int li = s * 256 + tid;
            int k = li >> 5, dloc = li & 31;
            lds2[k * 32 + dloc] = f2b(W2[k * 2304 + (w * 32 + dloc) * 9 + rr]);
        }
        __syncthreads();
        u16* ob = W2f + (rr * 8 + w) * 8192;
#pragma unroll
        for (int s = 0; s < 32; ++s) {
            const int o = s * 256 + tid;          // 0..8191
            const int e = o & 7;
            const int ln = (o >> 3) & 63;
            const int j = (o >> 9) & 1;
            const int kc = o >> 10;
            const int k = kc * 32 + (ln >> 4) * 8 + e;
            const int dloc = j * 16 + (ln & 15);
            ob[o] = lds2[k * 32 + dloc];
        }
    } else {                     // ---- b2 permute ----
        int idx = (bid - 1144) * 256 + tid;
        if (idx < 2304) b2p[idx] = b2[(idx & 255) * 9 + (idx >> 8)];
    }
}

// ============================================================
// Fused kernel v4: 224 blocks x 512 threads (8 waves), 112 rows/block
// (= exactly 2 image rows; 28 blocks per batch image). 1 block/CU,
// perfectly balanced grid (224 <= 256 CUs, zero multi-round tail).
// __launch_bounds__(512,2) -> 256 regs/wave: tvreg[7] + double-buffered
// B-frag prefetch all register-resident (R3's (512,4) starved arch-VGPRs
// to 64 and exposed L2 latency on every weight fetch).
// Wave w owns output cols [w*32,w*32+32) = h1 kc-slab w.
// LDS: As/Us [kc:8][row:112][slot:4][8 u16] = 57344 B each (114 KB).
// Swizzle (from R3, conflict-free): data(row,slot) at slot^((row>>1)&3);
// staging pre-swizzles the GLOBAL source (rule #21), reads/writes use
// the same XOR. Staging: wave w stages kc=w slab, 7 x load16 per lane.
// Barriers: 2/rr in phase 2 (sigmoid->u-pass is same-wave, no barrier).
// ============================================================
__global__ __launch_bounds__(512, 2) void k_fused(
    const u16* __restrict__ xtp, const u16* __restrict__ W1f,
    const u16* __restrict__ W2f, const u16* __restrict__ W3f,
    const float* __restrict__ b1, const float* __restrict__ b2p,
    const float* __restrict__ b3, float* __restrict__ out) {
    __shared__ __align__(16) u16 As[28672];  // 57344 B
    __shared__ __align__(16) u16 Us[28672];  // 57344 B

    const int tid = threadIdx.x;
    const int wave = tid >> 6;
    const int lane = tid & 63;
    const int fr = lane & 15;
    const int fq = lane >> 4;

    const int bid = blockIdx.x;
    const int b = bid / 28;              // batch
    const int h0 = (bid - b * 28) * 2;   // first image row of the block
    const int l0 = bid * 112;            // global output row base

    // per-thread staging/u-pass chunk addresses: kc = wave; chunk m = q*64+lane,
    // row = m>>2 (0..111), c8 = m&3; global channel pre-swizzled.
    int roffs[7];
#pragma unroll
    for (int q = 0; q < 7; ++q) {
        const int m = q * 64 + lane;
        const int row = m >> 2;
        const int c8 = m & 3;
        const int dh = row / 56;
        const int w = row - dh * 56;
        const int swz = c8 ^ ((row >> 1) & 3);
        roffs[q] = ((b * 58 + h0 + dh + 1) * 58 + (w + 1)) * 256 + wave * 32 + swz * 8;
    }
    // A-frag read offset within a kc-slab (slot = fq ^ ((fr>>1)&3))
    const int aoff = fr * 32 + ((fq ^ ((fr >> 1) & 3)) * 8);
    auto shiftOf = [](int rr) { return ((rr / 3 - 1) * 58 + (rr % 3) - 1) * 256; };
    auto stage = [&](u16* buf, int shift) {
        u16* dst = buf + wave * 3584 + lane * 8;
#pragma unroll
        for (int q = 0; q < 7; ++q)
            load16(xtp + roffs[q] + shift, dst + q * 512);
    };
    // swizzled epilogue u32-write index (u16 units) within kc=wave slab
    auto ewidx = [&](int i, int j, int r) {
        const int row = i * 16 + fq * 4 + r;
        const int sl = (j * 2 + (fr >> 3)) ^ ((fq * 2 + (r >> 1)) & 3);
        return row * 32 + sl * 8 + (fr & 7);
    };

    accfrag_t acc[7][2], accO[7][2];
#pragma unroll
    for (int i = 0; i < 7; ++i)
#pragma unroll
        for (int j = 0; j < 2; ++j) {
            acc[i][j] = (accfrag_t)0.f;
            accO[i][j] = (accfrag_t)0.f;
        }

    // ---------------- phase 1: h1 = relu(t @ W1 + b1), double-buffered ----
    const u16* w1p = W1f + wave * 73728 + lane * 8;
    stage(As, shiftOf(0));
    for (int rr = 0; rr < 9; ++rr) {
        u16* cur = (rr & 1) ? Us : As;
        u16* nxt = (rr & 1) ? As : Us;
        __syncthreads();   // cur slab visible (and nxt's readers from rr-1 done)
        if (rr < 8) stage(nxt, shiftOf(rr + 1));   // in flight during MFMA
        bfrag_t bf[2][2];
#pragma unroll
        for (int j = 0; j < 2; ++j)
            bf[0][j] = *(const bfrag_t*)(w1p + ((rr * 8 + 0) * 2 + j) * 512);
#pragma unroll
        for (int kc = 0; kc < 8; ++kc) {
            if (kc < 7) {      // prefetch next kc's B-frags (hidden under MFMA)
#pragma unroll
                for (int j = 0; j < 2; ++j)
                    bf[(kc + 1) & 1][j] =
                        *(const bfrag_t*)(w1p + ((rr * 8 + kc + 1) * 2 + j) * 512);
            }
            bfrag_t af[7];
#pragma unroll
            for (int i = 0; i < 7; ++i)
                af[i] = *(const bfrag_t*)(cur + kc * 3584 + i * 512 + aoff);
#pragma unroll
            for (int i = 0; i < 7; ++i)
#pragma unroll
                for (int j = 0; j < 2; ++j)
                    acc[i][j] = __builtin_amdgcn_mfma_f32_16x16x32_bf16(
                        af[i], bf[kc & 1][j], acc[i][j], 0, 0, 0);
        }
    }
    // h1 epilogue: relu, pair-pack (cvt_pk), into As kc=wave slab (swizzled)
    __syncthreads();
#pragma unroll
    for (int i = 0; i < 7; ++i) {
#pragma unroll
        for (int j = 0; j < 2; ++j) {
            const float bv = b1[wave * 32 + j * 16 + fr];
#pragma unroll
            for (int r = 0; r < 4; ++r) {
                float v = acc[i][j][r] + bv;
                v = v > 0.f ? v : 0.f;
                const float vh = __shfl_down(v, 1);
                if (!(lane & 1))
                    *(u32*)&As[wave * 3584 + ewidx(i, j, r)] = pkbf16(v, vh);
            }
        }
    }
    __syncthreads();

    // ---------------- phase 2: per rr slab ----------------
    const u16* w3p = W3f + wave * 73728 + lane * 8;
    for (int rr = 0; rr < 9; ++rr) {
        const int shift = shiftOf(rr);
        // tv prefetch (independent of 2a) — hidden under the MFMA below
        u32x4 tvreg[7];
#pragma unroll
        for (int q = 0; q < 7; ++q)
            tvreg[q] = *(const u32x4*)(xtp + roffs[q] + shift);
        // 2a: z = h1 @ W2slab (K=256; reads As only)
#pragma unroll
        for (int i = 0; i < 7; ++i)
#pragma unroll
            for (int j = 0; j < 2; ++j) acc[i][j] = (accfrag_t)0.f;
        const u16* w2p = W2f + (rr * 8 + wave) * 8192 + lane * 8;
        {
            bfrag_t bf[2][2];
#pragma unroll
            for (int j = 0; j < 2; ++j)
                bf[0][j] = *(const bfrag_t*)(w2p + (0 * 2 + j) * 512);
#pragma unroll
            for (int kc = 0; kc < 8; ++kc) {
                if (kc < 7) {
#pragma unroll
                    for (int j = 0; j < 2; ++j)
                        bf[(kc + 1) & 1][j] =
                            *(const bfrag_t*)(w2p + ((kc + 1) * 2 + j) * 512);
                }
                bfrag_t af[7];
#pragma unroll
                for (int i = 0; i < 7; ++i)
                    af[i] = *(const bfrag_t*)(As + kc * 3584 + i * 512 + aoff);
#pragma unroll
                for (int i = 0; i < 7; ++i)
#pragma unroll
                    for (int j = 0; j < 2; ++j)
                        acc[i][j] = __builtin_amdgcn_mfma_f32_16x16x32_bf16(
                            af[i], bf[kc & 1][j], acc[i][j], 0, 0, 0);
            }
        }
        __syncthreads();  // prev rr's 2b reads of Us done
        // sigmoid pair-pack -> Us kc=wave slab (swizzled); same-wave consumer
#pragma unroll
        for (int i = 0; i < 7; ++i) {
#pragma unroll
            for (int j = 0; j < 2; ++j) {
                const float bv = b2p[rr * 256 + wave * 32 + j * 16 + fr];
#pragma unroll
                for (int r = 0; r < 4; ++r) {
                    const float z = acc[i][j][r] + bv;
                    const float s = __builtin_amdgcn_rcpf(1.f + __expf(-z));
                    const float sh = __shfl_down(s, 1);
                    if (!(lane & 1))
                        *(u32*)&Us[wave * 3584 + ewidx(i, j, r)] = pkbf16(s, sh);
                }
            }
        }
        // u = t * s : this wave's 7 staged chunks live in kc=wave slab,
        // written by THIS wave above -> no barrier needed (lgkmcnt only).
#pragma unroll
        for (int q = 0; q < 7; ++q) {
            const int idx = wave * 3584 + (q * 64 + lane) * 8;
            u32x4 sv = *(const u32x4*)(Us + idx);
            u32x4 rv;
#pragma unroll
            for (int e = 0; e < 4; ++e)
                rv[e] = pkbf16(blo(sv[e]) * blo(tvreg[q][e]),
                               bhi(sv[e]) * bhi(tvreg[q][e]));
            *(u32x4*)(Us + idx) = rv;
        }
        __syncthreads();  // u visible to all waves
        // 2b: accO += u @ W3slab (K=256)
        {
            bfrag_t bf[2][2];
#pragma unroll
            for (int j = 0; j < 2; ++j)
                bf[0][j] = *(const bfrag_t*)(w3p + ((rr * 8 + 0) * 2 + j) * 512);
#pragma unroll
            for (int kc = 0; kc < 8; ++kc) {
                if (kc < 7) {
#pragma unroll
                    for (int j = 0; j < 2; ++j)
                        bf[(kc + 1) & 1][j] =
                            *(const bfrag_t*)(w3p + ((rr * 8 + kc + 1) * 2 + j) * 512);
                }
                bfrag_t af[7];
#pragma unroll
                for (int i = 0; i < 7; ++i)
                    af[i] = *(const bfrag_t*)(Us + kc * 3584 + i * 512 + aoff);
#pragma unroll
                for (int i = 0; i < 7; ++i)
#pragma unroll
                    for (int j = 0; j < 2; ++j)
                        accO[i][j] = __builtin_amdgcn_mfma_f32_16x16x32_bf16(
                            af[i], bf[kc & 1][j], accO[i][j], 0, 0, 0);
            }
        }
    }

    // ---------------- final epilogue: out = accO + b3 ----------------
#pragma unroll
    for (int i = 0; i < 7; ++i) {
#pragma unroll
        for (int j = 0; j < 2; ++j) {
            const int col = wave * 32 + j * 16 + fr;
            const float bv = b3[col];
#pragma unroll
            for (int r = 0; r < 4; ++r) {
                const float v = accO[i][j][r] + bv;
                const float vh = __shfl_down(v, 1);
                if (!(lane & 1)) {
                    float2 st = make_float2(v, vh);
                    *(float2*)(out + (size_t)(l0 + i * 16 + fq * 4 + r) * 256 + col) = st;
                }
            }
        }
    }
}

extern "C" void kernel_launch(void* const* d_in, const int* in_sizes, int n_in,
                              void* d_out, int out_size, void* d_ws, size_t ws_size,
                              hipStream_t stream) {
    const float* x  = (const float*)d_in[0];
    const float* W1 = (const float*)d_in[1];
    const float* b1 = (const float*)d_in[2];
    const float* W2 = (const float*)d_in[3];
    const float* b2 = (const float*)d_in[4];
    const float* W3 = (const float*)d_in[5];
    const float* b3 = (const float*)d_in[6];
    float* out = (float*)d_out;

    char* ws = (char*)d_ws;
    u16* xtp = (u16*)ws;  ws += (size_t)8 * 58 * 58 * 256 * 2;
    u16* W1f = (u16*)ws;  ws += (size_t)589824 * 2;
    u16* W2f = (u16*)ws;  ws += (size_t)589824 * 2;
    u16* W3f = (u16*)ws;  ws += (size_t)589824 * 2;
    float* b2p = (float*)ws;

    k_prep<<<1153, 256, 0, stream>>>(x, W1, W2, W3, b2, xtp, W1f, W2f, W3f, b2p);
    k_fused<<<224, 512, 0, stream>>>(xtp, W1f, W2f, W3f, b1, b2p, b3, out);
}